// Round 7
// baseline (572.185 us; speedup 1.0000x reference)
//
#include <hip/hip_runtime.h>

// TxGNN R13: rebuild the node GEMMs with the msg-proven techniques.
// R10/R12 post-mortem: msg intra-block restructurings all neutral -> msg ~66us
// is gather-bound (irreducible). The larger target is the ~430us non-msg
// aggregate: 6 GEMMs with 8-barrier K-loops, LDS B-staging, fp32 A + in-loop
// f2bf. R13: (1) frag-linear B loaded DIRECT from global (R9 win, L1-hot);
// (2) full-K A staged once -> 1 barrier; (3) bf16 A inputs (xb/hb) -> half
// traffic, no in-loop converts, h fp32 never materialized; (4) xw-gemm2 fused
// into agg-gemm1 as phase-B MFMA via LDS (one fewer dispatch). msg = R10 form
// (best measured). Bit-identical numerics.

constexpr int N_NODES = 50000;
constexpr int N_EDGES = 640000;
constexpr int DF = 128;
constexpr int DE = 64;

typedef short bf16x8 __attribute__((ext_vector_type(8)));
typedef float f32x4 __attribute__((ext_vector_type(4)));

__device__ __forceinline__ void fatomic(float* p, float v) {
#if defined(__AMDGCN__)
    unsafeAtomicAdd(p, v);
#else
    atomicAdd(p, v);
#endif
}

__device__ __forceinline__ unsigned short f2bf(float f) {
    union { float f; unsigned u; } v; v.f = f;
    unsigned r = (v.u + 0x7FFFu + ((v.u >> 16) & 1u)) >> 16;
    return (unsigned short)r;
}
__device__ __forceinline__ float b2f(unsigned short u) {
    union { unsigned u; float f; } v; v.u = (unsigned)u << 16;
    return v.f;
}

// ---------------------------------------------------------------------------
// Frag-linear weight builder. For W[K][128], element j of buffer T:
//   e=j&7, lane=(j>>3)&63, kh=(j>>9)&1, ctks=j>>10, ks=ctks%nks, ct=ctks/nks
//   k = k0 + ks*64 + kh*32 + (lane>>4)*8 + e ; n = ct*16 + (lane&15)
// Consumers load bf16x8 at vec-index ((ct*nks+ks)*2+kh)*64+lane.
__device__ __forceinline__ void frag_fill(const float* __restrict__ W,
                                          unsigned short* __restrict__ T,
                                          int k0, int nks, int j) {
    const int e    = j & 7;
    const int lane = (j >> 3) & 63;
    const int kh   = (j >> 9) & 1;
    const int ctks = j >> 10;
    const int ks   = ctks % nks;
    const int ct   = ctks / nks;
    const int k = k0 + ks * 64 + kh * 32 + (lane >> 4) * 8 + e;
    const int n = ct * 16 + (lane & 15);
    T[j] = f2bf(W[k * 128 + n]);
}

// All six frag-linear weight buffers in one launch (114688 threads).
__global__ __launch_bounds__(256)
void wconv_kernel(const float* __restrict__ Wm1, const float* __restrict__ Wa1,
                  const float* __restrict__ Wm2, const float* __restrict__ Wa2,
                  unsigned short* __restrict__ Wf1, unsigned short* __restrict__ Bf1,
                  unsigned short* __restrict__ Wfa1,
                  unsigned short* __restrict__ Wf2, unsigned short* __restrict__ Bf2,
                  unsigned short* __restrict__ Wfa2) {
    int i = blockIdx.x * blockDim.x + threadIdx.x;
    if (i < 16384)       frag_fill(Wm1, Wf1,  0,   2, i);
    else if (i < 24576)  frag_fill(Wm1, Bf1,  128, 1, i - 16384);
    else if (i < 57344)  frag_fill(Wa1, Wfa1, 0,   4, i - 24576);
    else if (i < 73728)  frag_fill(Wm2, Wf2,  0,   2, i - 57344);
    else if (i < 81920)  frag_fill(Wm2, Bf2,  128, 1, i - 73728);
    else if (i < 114688) frag_fill(Wa2, Wfa2, 0,   4, i - 81920);
}

// x -> bf16 once (8 elems/thread).
__global__ __launch_bounds__(256)
void f2bf_kernel(const float* __restrict__ in, unsigned short* __restrict__ out,
                 int n8) {
    int i = blockIdx.x * 256 + threadIdx.x;
    if (i < n8) {
        float4 f0 = *(const float4*)(in + (size_t)i * 8);
        float4 f1 = *(const float4*)(in + (size_t)i * 8 + 4);
        ushort4 o0, o1;
        o0.x = f2bf(f0.x); o0.y = f2bf(f0.y); o0.z = f2bf(f0.z); o0.w = f2bf(f0.w);
        o1.x = f2bf(f1.x); o1.y = f2bf(f1.y); o1.z = f2bf(f1.z); o1.w = f2bf(f1.w);
        *(ushort4*)(out + (size_t)i * 8)     = o0;
        *(ushort4*)(out + (size_t)i * 8 + 4) = o1;
    }
}

// CSR build: histogram -> 3-kernel scan -> permutation scatter.
__global__ __launch_bounds__(256)
void hist_kernel(const int* __restrict__ dst, int* __restrict__ hist) {
    int i = blockIdx.x * blockDim.x + threadIdx.x;
    if (i < N_EDGES) atomicAdd(&hist[dst[i]], 1);
}

__global__ __launch_bounds__(256)
void scan1_kernel(const int* __restrict__ hist, int* __restrict__ excl,
                  int* __restrict__ blksum, int n) {
    __shared__ int buf[256];
    const int t = threadIdx.x;
    const int i = blockIdx.x * 256 + t;
    int v = (i < n) ? hist[i] : 0;
    buf[t] = v;
    __syncthreads();
    #pragma unroll
    for (int off = 1; off < 256; off <<= 1) {
        int x = (t >= off) ? buf[t - off] : 0;
        __syncthreads();
        buf[t] += x;
        __syncthreads();
    }
    if (i < n) excl[i] = buf[t] - v;
    if (t == 255) blksum[blockIdx.x] = buf[255];
}

__global__ __launch_bounds__(256)
void scan2_kernel(int* __restrict__ blksum, int nb) {
    __shared__ int buf[256];
    const int t = threadIdx.x;
    int v = (t < nb) ? blksum[t] : 0;
    buf[t] = v;
    __syncthreads();
    #pragma unroll
    for (int off = 1; off < 256; off <<= 1) {
        int x = (t >= off) ? buf[t - off] : 0;
        __syncthreads();
        buf[t] += x;
        __syncthreads();
    }
    if (t < nb) blksum[t] = buf[t] - v;
}

__global__ __launch_bounds__(256)
void scan3_kernel(int* __restrict__ excl, const int* __restrict__ blksum, int n) {
    const int i = blockIdx.x * 256 + threadIdx.x;
    if (i < n) excl[i] += blksum[blockIdx.x];
}

__global__ __launch_bounds__(256)
void build_kernel(const int* __restrict__ src, const int* __restrict__ dst,
                  int* __restrict__ cursor,
                  int* __restrict__ perm, int* __restrict__ srcs,
                  int* __restrict__ dsts) {
    int e = blockIdx.x * blockDim.x + threadIdx.x;
    if (e < N_EDGES) {
        const int d = dst[e];
        const int pos = atomicAdd(&cursor[d], 1);
        perm[pos] = e;
        srcs[pos] = src[e];
        dsts[pos] = d;
    }
}

// ea_s[p] = bf16(ea[perm[p]]) — sorted, streaming-friendly, reused 2x.
__global__ __launch_bounds__(256)
void ea_sort_kernel(const float* __restrict__ ea, const int* __restrict__ perm,
                    unsigned short* __restrict__ ea_s) {
    const int t = threadIdx.x;
    const int p = blockIdx.x * 16 + (t >> 4);
    const int c = (t & 15) * 4;
    const int e = perm[p];
    float4 f = *(const float4*)(ea + (size_t)e * DE + c);
    ushort4 o;
    o.x = f2bf(f.x); o.y = f2bf(f.y); o.z = f2bf(f.z); o.w = f2bf(f.w);
    *(ushort4*)(ea_s + (size_t)p * DE + c) = o;
}

// ---------------------------------------------------------------------------
// Node GEMM v2: full-K A staged once (1 barrier), B frag-linear direct from
// global (L1-hot). C[i,:] = act( A[i,:] @ W + bias ).
//   NKS=2: K=128, A1 bf16.  NKS=4: K=256, A1 fp32 (aggr) cols 0..127,
//   A2 bf16 cols 128..255.
// OUTMODE: 0 = fp32 out; 1 = bf16 out; 2 = bf16 out + fused phase-B
//   (CB[i,:] = bf16( h[i,:] @ WfB ), h routed through LDS).
// ---------------------------------------------------------------------------
template<int NKS, bool A1F32, bool RELU, bool BIAS, int OUTMODE>
__global__ __launch_bounds__(256)
void gemm2(const void* __restrict__ A1v, const unsigned short* __restrict__ A2,
           const unsigned short* __restrict__ Wf, const float* __restrict__ bias,
           void* __restrict__ Cv,
           const unsigned short* __restrict__ WfB, unsigned short* __restrict__ CB,
           int n)
{
    constexpr int K = NKS * 64;
    constexpr int STRIDE = K + 8;
    __shared__ unsigned short Asm[64][STRIDE];

    const int r0   = blockIdx.x * 64;
    const int t    = threadIdx.x;
    const int wave = t >> 6;
    const int lane = t & 63;
    const int quad = lane >> 4;
    const int l15  = lane & 15;

    // ---- stage A (full K), 4 threads per row ----
    {
        const int row = t >> 2;
        int rg = r0 + row; if (rg >= n) rg = n - 1;
        const int c0 = (t & 3) * 32;
        if (A1F32) {
            const float* sp = (const float*)A1v + (size_t)rg * 128 + c0;
            #pragma unroll
            for (int h = 0; h < 2; ++h) {
                union { unsigned short us[16]; uint4 q[2]; } tmp;
                #pragma unroll
                for (int u = 0; u < 4; ++u) {
                    float4 f = *(const float4*)(sp + h * 16 + u * 4);
                    tmp.us[u * 4 + 0] = f2bf(f.x);
                    tmp.us[u * 4 + 1] = f2bf(f.y);
                    tmp.us[u * 4 + 2] = f2bf(f.z);
                    tmp.us[u * 4 + 3] = f2bf(f.w);
                }
                *(uint4*)&Asm[row][c0 + h * 16]     = tmp.q[0];
                *(uint4*)&Asm[row][c0 + h * 16 + 8] = tmp.q[1];
            }
            // cols 128..255 from bf16 A2
            const unsigned short* sp2 = A2 + (size_t)rg * 128 + c0;
            uint4 q0 = *(const uint4*)(sp2);
            uint4 q1 = *(const uint4*)(sp2 + 8);
            uint4 q2 = *(const uint4*)(sp2 + 16);
            uint4 q3 = *(const uint4*)(sp2 + 24);
            *(uint4*)&Asm[row][128 + c0]      = q0;
            *(uint4*)&Asm[row][128 + c0 + 8]  = q1;
            *(uint4*)&Asm[row][128 + c0 + 16] = q2;
            *(uint4*)&Asm[row][128 + c0 + 24] = q3;
        } else {
            const unsigned short* sp = (const unsigned short*)A1v + (size_t)rg * 128 + c0;
            uint4 q0 = *(const uint4*)(sp);
            uint4 q1 = *(const uint4*)(sp + 8);
            uint4 q2 = *(const uint4*)(sp + 16);
            uint4 q3 = *(const uint4*)(sp + 24);
            *(uint4*)&Asm[row][c0]      = q0;
            *(uint4*)&Asm[row][c0 + 8]  = q1;
            *(uint4*)&Asm[row][c0 + 16] = q2;
            *(uint4*)&Asm[row][c0 + 24] = q3;
        }
    }
    __syncthreads();

    // ---- MFMA: A from LDS, B frag-linear direct ----
    const bf16x8* Bv = (const bf16x8*)Wf;
    f32x4 acc[8];
    #pragma unroll
    for (int ct = 0; ct < 8; ++ct) acc[ct] = (f32x4)(0.f);
    #pragma unroll
    for (int ks = 0; ks < NKS; ++ks) {
        bf16x8 a0 = *(const bf16x8*)&Asm[wave * 16 + l15][ks * 64 + quad * 8];
        bf16x8 a1 = *(const bf16x8*)&Asm[wave * 16 + l15][ks * 64 + 32 + quad * 8];
        #pragma unroll
        for (int ct = 0; ct < 8; ++ct) {
            bf16x8 b0 = Bv[((ct * NKS + ks) * 2 + 0) * 64 + lane];
            bf16x8 b1 = Bv[((ct * NKS + ks) * 2 + 1) * 64 + lane];
            acc[ct] = __builtin_amdgcn_mfma_f32_16x16x32_bf16(a0, b0, acc[ct], 0, 0, 0);
            acc[ct] = __builtin_amdgcn_mfma_f32_16x16x32_bf16(a1, b1, acc[ct], 0, 0, 0);
        }
    }

    if (OUTMODE == 2) __syncthreads();   // all A-frag reads done before LDS reuse
    unsigned short (*Hs)[136] = (unsigned short(*)[136])Asm;

    // ---- epilogue ----
    #pragma unroll
    for (int ct = 0; ct < 8; ++ct) {
        const int col = ct * 16 + l15;
        const float bval = BIAS ? bias[col] : 0.f;
        #pragma unroll
        for (int reg = 0; reg < 4; ++reg) {
            const int row = r0 + wave * 16 + quad * 4 + reg;
            float v = acc[ct][reg] + bval;
            if (RELU) v = v > 0.f ? v : 0.f;
            if (OUTMODE == 0) {
                if (row < n) ((float*)Cv)[(size_t)row * 128 + col] = v;
            } else {
                const unsigned short hv = f2bf(v);
                if (row < n) ((unsigned short*)Cv)[(size_t)row * 128 + col] = hv;
                if (OUTMODE == 2) Hs[wave * 16 + quad * 4 + reg][col] = hv;
            }
        }
    }

    // ---- fused phase B: CB = bf16( h @ WfB ), K=128 ----
    if (OUTMODE == 2) {
        __syncthreads();
        const bf16x8* Bv2 = (const bf16x8*)WfB;
        f32x4 acc2[8];
        #pragma unroll
        for (int ct = 0; ct < 8; ++ct) acc2[ct] = (f32x4)(0.f);
        #pragma unroll
        for (int ks = 0; ks < 2; ++ks) {
            bf16x8 a0 = *(const bf16x8*)&Hs[wave * 16 + l15][ks * 64 + quad * 8];
            bf16x8 a1 = *(const bf16x8*)&Hs[wave * 16 + l15][ks * 64 + 32 + quad * 8];
            #pragma unroll
            for (int ct = 0; ct < 8; ++ct) {
                bf16x8 b0 = Bv2[((ct * 2 + ks) * 2 + 0) * 64 + lane];
                bf16x8 b1 = Bv2[((ct * 2 + ks) * 2 + 1) * 64 + lane];
                acc2[ct] = __builtin_amdgcn_mfma_f32_16x16x32_bf16(a0, b0, acc2[ct], 0, 0, 0);
                acc2[ct] = __builtin_amdgcn_mfma_f32_16x16x32_bf16(a1, b1, acc2[ct], 0, 0, 0);
            }
        }
        #pragma unroll
        for (int ct = 0; ct < 8; ++ct) {
            const int col = ct * 16 + l15;
            #pragma unroll
            for (int reg = 0; reg < 4; ++reg) {
                const int row = r0 + wave * 16 + quad * 4 + reg;
                if (row < n) CB[(size_t)row * 128 + col] = f2bf(acc2[ct][reg]);
            }
        }
    }
}

// ---------------------------------------------------------------------------
// Edge message (R10 form — best measured): MFMA with direct-A from ea_s,
// frag-linear B; coalesced xw prefetch; acc->Ms; add-pass; parallel
// segment-reduce with 4-way unroll.
// ---------------------------------------------------------------------------
__global__ __launch_bounds__(256, 4)
void msg_mfma(const unsigned short* __restrict__ xwb,   // [N,128] bf16
              const unsigned short* __restrict__ ea_s,  // [E,64] bf16 sorted
              const int*   __restrict__ srcs,
              const int*   __restrict__ dsts,
              const unsigned short* __restrict__ Bf,    // frag-linear bottom W
              const float* __restrict__ bias,
              float* __restrict__ aggr)
{
    __shared__ float Ms[64][132];      // 33792 B
    __shared__ int Ds[64];
    __shared__ int Rstart[64];
    __shared__ int Meta[3];            // nruns, dprev, dnext

    const int p0   = blockIdx.x * 64;
    const int t    = threadIdx.x;
    const int wave = t >> 6;
    const int lane = t & 63;
    const int quad = lane >> 4;
    const int l15  = lane & 15;
    const int tx   = t & 31;
    const int ty   = t >> 5;

    if (t < 64) {
        const int d  = dsts[p0 + t];
        const int dl = __shfl_up(d, 1);
        const bool head = (t == 0) || (d != dl);
        const unsigned long long mask = __ballot(head);
        const int idx = __popcll(mask & ((1ull << t) - 1ull));
        if (head) Rstart[idx] = t;
        if (t == 0) {
            Meta[0] = (int)__popcll(mask);
            Meta[1] = (p0 == 0) ? -1 : dsts[p0 - 1];
        }
        if (t == 1) Meta[2] = (p0 + 64 >= N_EDGES) ? -1 : dsts[p0 + 64];
        Ds[t] = d;
    }

    const int pbase = p0 + ty * 8;
    ushort4 xv[8];
    #pragma unroll
    for (int r = 0; r < 8; ++r) {
        const int s = srcs[pbase + r];
        xv[r] = *(const ushort4*)(xwb + (size_t)s * 128 + tx * 4);
    }

    const unsigned short* ap = ea_s + (size_t)(p0 + wave * 16 + l15) * DE + quad * 8;
    bf16x8 a0 = *(const bf16x8*)(ap);
    bf16x8 a1 = *(const bf16x8*)(ap + 32);

    const bf16x8* Bv = (const bf16x8*)Bf;
    f32x4 acc[8];
    #pragma unroll
    for (int ct = 0; ct < 8; ++ct) {
        bf16x8 b0 = Bv[(ct * 2 + 0) * 64 + lane];
        bf16x8 b1 = Bv[(ct * 2 + 1) * 64 + lane];
        acc[ct] = __builtin_amdgcn_mfma_f32_16x16x32_bf16(a0, b0, (f32x4)(0.f), 0, 0, 0);
        acc[ct] = __builtin_amdgcn_mfma_f32_16x16x32_bf16(a1, b1, acc[ct], 0, 0, 0);
    }

    #pragma unroll
    for (int ct = 0; ct < 8; ++ct)
        #pragma unroll
        for (int reg = 0; reg < 4; ++reg)
            Ms[wave * 16 + quad * 4 + reg][ct * 16 + l15] = acc[ct][reg];
    __syncthreads();

    float bv[4];
    *(float4*)bv = *(const float4*)(bias + tx * 4);
    #pragma unroll
    for (int r = 0; r < 8; ++r) {
        float4 m = *(float4*)&Ms[ty * 8 + r][tx * 4];
        float v0 = m.x + b2f(xv[r].x) + bv[0];
        float v1 = m.y + b2f(xv[r].y) + bv[1];
        float v2 = m.z + b2f(xv[r].z) + bv[2];
        float v3 = m.w + b2f(xv[r].w) + bv[3];
        m.x = v0 > 0.f ? v0 : 0.f;
        m.y = v1 > 0.f ? v1 : 0.f;
        m.z = v2 > 0.f ? v2 : 0.f;
        m.w = v3 > 0.f ? v3 : 0.f;
        *(float4*)&Ms[ty * 8 + r][tx * 4] = m;
    }
    __syncthreads();

    {
        const int nr    = Meta[0];
        const int dprev = Meta[1];
        const int dnext = Meta[2];
        const int g4    = tx * 4;
        for (int run = t >> 5; run < nr; run += 8) {
            const int start = Rstart[run];
            const int end   = (run + 1 < nr) ? Rstart[run + 1] : 64;
            const int d     = Ds[start];
            float4 s0 = {0.f, 0.f, 0.f, 0.f};
            float4 s1 = s0, s2 = s0, s3 = s0;
            int r = start;
            for (; r + 4 <= end; r += 4) {
                float4 v0 = *(float4*)&Ms[r + 0][g4];
                float4 v1 = *(float4*)&Ms[r + 1][g4];
                float4 v2 = *(float4*)&Ms[r + 2][g4];
                float4 v3 = *(float4*)&Ms[r + 3][g4];
                s0.x += v0.x; s0.y += v0.y; s0.z += v0.z; s0.w += v0.w;
                s1.x += v1.x; s1.y += v1.y; s1.z += v1.z; s1.w += v1.w;
                s2.x += v2.x; s2.y += v2.y; s2.z += v2.z; s2.w += v2.w;
                s3.x += v3.x; s3.y += v3.y; s3.z += v3.z; s3.w += v3.w;
            }
            for (; r < end; ++r) {
                float4 v = *(float4*)&Ms[r][g4];
                s0.x += v.x; s0.y += v.y; s0.z += v.z; s0.w += v.w;
            }
            float4 s;
            s.x = (s0.x + s1.x) + (s2.x + s3.x);
            s.y = (s0.y + s1.y) + (s2.y + s3.y);
            s.z = (s0.z + s1.z) + (s2.z + s3.z);
            s.w = (s0.w + s1.w) + (s2.w + s3.w);
            float* ap2 = aggr + (size_t)d * 128 + g4;
            if ((start == 0 && d == dprev) || (end == 64 && d == dnext)) {
                fatomic(ap2 + 0, s.x); fatomic(ap2 + 1, s.y);
                fatomic(ap2 + 2, s.z); fatomic(ap2 + 3, s.w);
            } else {
                *(float4*)ap2 = s;
            }
        }
    }
}

// ---------------------------------------------------------------------------
extern "C" void kernel_launch(void* const* d_in, const int* in_sizes, int n_in,
                              void* d_out, int out_size, void* d_ws, size_t ws_size,
                              hipStream_t stream) {
    const float* x    = (const float*)d_in[0];
    const int*   eidx = (const int*)  d_in[1];
    const float* ea   = (const float*)d_in[2];
    const float* Wm1  = (const float*)d_in[3];
    const float* bm1  = (const float*)d_in[4];
    const float* Wa1  = (const float*)d_in[5];
    const float* ba1  = (const float*)d_in[6];
    const float* Wm2  = (const float*)d_in[7];
    const float* bm2  = (const float*)d_in[8];
    const float* Wa2  = (const float*)d_in[9];
    const float* ba2  = (const float*)d_in[10];
    float* out = (float*)d_out;

    const int* src = eidx;
    const int* dst = eidx + N_EDGES;

    const size_t nodeBuf = (size_t)N_NODES * DF;       // 6.4M elems
    float* aggr = (float*)d_ws;                                // 25.6 MB
    unsigned short* xwb  = (unsigned short*)(aggr + nodeBuf);  // 12.8 MB
    unsigned short* ea_s = xwb + nodeBuf;                      // 81.9 MB
    unsigned short* xb   = ea_s + (size_t)N_EDGES * DE;        // 12.8 MB
    unsigned short* hb   = xb + nodeBuf;                       // 12.8 MB
    int* cursor = (int*)(hb + nodeBuf);
    int* perm   = cursor + N_NODES;
    int* srcs   = perm + N_EDGES;
    int* dsts   = srcs + N_EDGES;
    unsigned short* Wf1  = (unsigned short*)(dsts + N_EDGES);  // 16384
    unsigned short* Bf1  = Wf1 + 16384;                        // 8192
    unsigned short* Wfa1 = Bf1 + 8192;                         // 32768
    unsigned short* Wf2  = Wfa1 + 32768;                       // 16384
    unsigned short* Bf2  = Wf2 + 16384;                        // 8192
    unsigned short* Wfa2 = Bf2 + 8192;                         // 32768
    int* blksum = (int*)(Wfa2 + 32768);

    const int gN = (N_NODES + 63) / 64;       // 782
    const int gE = N_EDGES / 64;              // 10000
    const int gS = (N_NODES + 255) / 256;     // 196
    dim3 blk(256);

    // ---- weights -> frag-linear bf16 ; x -> bf16 ----
    wconv_kernel<<<448, blk, 0, stream>>>(Wm1, Wa1, Wm2, Wa2,
                                          Wf1, Bf1, Wfa1, Wf2, Bf2, Wfa2);
    f2bf_kernel<<<(800000 + 255) / 256, blk, 0, stream>>>(x, xb, 800000);

    // ---- CSR permutation + sorted bf16 edge features ----
    hipMemsetAsync(dsts, 0, N_NODES * sizeof(int), stream);    // hist scratch
    hist_kernel<<<(N_EDGES + 255) / 256, blk, 0, stream>>>(dst, dsts);
    scan1_kernel<<<gS, blk, 0, stream>>>(dsts, cursor, blksum, N_NODES);
    scan2_kernel<<<1, blk, 0, stream>>>(blksum, gS);
    scan3_kernel<<<gS, blk, 0, stream>>>(cursor, blksum, N_NODES);
    build_kernel<<<(N_EDGES + 255) / 256, blk, 0, stream>>>(
        src, dst, cursor, perm, srcs, dsts);
    ea_sort_kernel<<<N_EDGES / 16, blk, 0, stream>>>(ea, perm, ea_s);

    // ---- layer 1 ----
    hipMemsetAsync(aggr, 0, nodeBuf * sizeof(float), stream);
    gemm2<2, false, false, false, 1><<<gN, blk, 0, stream>>>(
        xb, nullptr, Wf1, nullptr, xwb, nullptr, nullptr, N_NODES);
    msg_mfma<<<gE, blk, 0, stream>>>(
        xwb, ea_s, srcs, dsts, Bf1, bm1, aggr);
    // agg-gemm1 fused: hb = bf16(relu(cat(aggr,x)@Wa1+ba1)); xwb = bf16(h@Wm2top)
    gemm2<4, true, true, true, 2><<<gN, blk, 0, stream>>>(
        aggr, xb, Wfa1, ba1, hb, Wf2, xwb, N_NODES);

    // ---- layer 2 ----
    hipMemsetAsync(aggr, 0, nodeBuf * sizeof(float), stream);
    msg_mfma<<<gE, blk, 0, stream>>>(
        xwb, ea_s, srcs, dsts, Bf2, bm2, aggr);
    gemm2<4, true, true, true, 0><<<gN, blk, 0, stream>>>(
        aggr, hb, Wfa2, ba2, out, nullptr, nullptr, N_NODES);
}